// Round 10
// baseline (116.037 us; speedup 1.0000x reference)
//
#include <hip/hip_runtime.h>
#include <math.h>

// Problem constants (from reference). All float tensors f32; mask int; out f32.
#define BB 64
#define NN 128
#define DD 128
#define RR 4096
#define KD 64

typedef _Float16 f16x8 __attribute__((ext_vector_type(8)));
typedef _Float16 f16x4 __attribute__((ext_vector_type(4)));
typedef float    float4v __attribute__((ext_vector_type(4)));

// ---- ws layout (byte offsets) ----
#define WS_E_OFF   0                                  // E f16 (R*D), 1 MB
#define WS_S_OFF   (1048576)                          // S f16 compacted, 2 MB
#define WS_CG_OFF  (3145728)                          // colGeo float4 (R), 64 KB
#define WS_RG_OFF  (3145728 + 65536)                  // rowGeo float4 (B*128), 128 KB
#define WS_TAB_OFF (3145728 + 65536 + 131072)         // tab2 float2 (KD), 512 B
#define WS_V_OFF   (3145728 + 65536 + 131072 + 512)   // V int (B), 256 B

#define D2R_C    0.017453292519943295f                // pi/180
#define HSC_C    (0.008726646259971648f * 4013.73f)   // (pi/360)*2*Re*(63/200)
#define L2E_C    1.4426950408889634f
#define SCALE2_C (0.08838834764831845f * 1.4426950408889634f)
#define LN2_C    0.6931471805599453f

// Pre-pass: E->f16, per-b valid-row compaction of S (f32->f16), per-b rowGeo,
// per-r colGeo, exp2-domain bias table. 593 blocks x 256.
__global__ __launch_bounds__(256)
void prep_kernel(const float* __restrict__ S, const float* __restrict__ E,
                 const float* __restrict__ tlat, const float* __restrict__ tlon,
                 const float* __restrict__ cent, const int* __restrict__ kpm,
                 const float* __restrict__ Etab, char* __restrict__ wsb) {
    const int blk = blockIdx.x, tid = threadIdx.x;
    if (blk < 512) {                       // E convert: 512*256 = 131072 float4s
        int i = blk * 256 + tid;
        float4 v = ((const float4*)E)[i];
        f16x4 h = {(_Float16)v.x, (_Float16)v.y, (_Float16)v.z, (_Float16)v.w};
        ((f16x4*)(wsb + WS_E_OFF))[i] = h;
    } else if (blk < 528) {                // colGeo: 16*256 = 4096
        int r = (blk - 512) * 256 + tid;
        float cla = cent[2 * r], clo = cent[2 * r + 1];
        ((float4*)(wsb + WS_CG_OFF))[r] =
            make_float4(cla * HSC_C, clo * HSC_C, cosf(cla * D2R_C), 0.0f);
    } else if (blk == 528) {               // tab2
        if (tid < KD) {
            float lo = Etab[tid];
            float hi = Etab[tid < KD - 1 ? tid + 1 : KD - 1];
            ((float2*)(wsb + WS_TAB_OFF))[tid] =
                make_float2(lo * L2E_C, (hi - lo) * L2E_C);
        }
    } else {                               // per-b compaction: blk-529 = b
        __shared__ int idx[128];
        __shared__ unsigned long long smask[2];
        const int b = blk - 529;
        const int wv = tid >> 6, lane = tid & 63;
        if (tid < 128) {
            bool valid = (kpm[b * NN + tid] == 0);
            unsigned long long m = __ballot(valid);
            if (lane == 0) smask[wv] = m;
        }
        __syncthreads();
        const unsigned long long m0 = smask[0], m1 = smask[1];
        const int c0 = __popcll(m0);
        const int V  = c0 + __popcll(m1);
        if (tid == 0) ((int*)(wsb + WS_V_OFF))[b] = V;
        if (tid < 128) {
            unsigned long long mw = (tid < 64) ? m0 : m1;
            int ln = tid & 63;
            if ((mw >> ln) & 1ull) {
                int pos = __popcll(mw & ((1ull << ln) - 1ull)) + (tid < 64 ? 0 : c0);
                idx[pos] = tid;
            }
        }
        __syncthreads();
        if (tid < 128) {                   // compacted row geo (pads cn=-1)
            float4 rg;
            if (tid < V) {
                int n = idx[tid];
                float la = tlat[b * NN + n], lo = tlon[b * NN + n];
                rg = make_float4(la * HSC_C, lo * HSC_C, cosf(la * D2R_C), 0.0f);
            } else rg = make_float4(0.0f, 0.0f, -1.0f, 0.0f);
            ((float4*)(wsb + WS_RG_OFF))[b * 128 + tid] = rg;
        }
        // compact-copy S rows, f32 -> f16
        f16x4* dst = (f16x4*)(wsb + WS_S_OFF) + (size_t)b * NN * (DD / 4);
        const float4* src = (const float4*)S + (size_t)b * NN * (DD / 4);
        for (int ch = tid; ch < V * 32; ch += 256) {
            int row = ch >> 5, cp = ch & 31;
            float4 v = src[idx[row] * 32 + cp];
            f16x4 h = {(_Float16)v.x, (_Float16)v.y, (_Float16)v.z, (_Float16)v.w};
            dst[row * 32 + cp] = h;
        }
    }
}

// One block per (b, group of 4 r-tiles of 64 cols). Grid 16x64 = 1024 blocks
// = exactly 4/CU, one dispatch round. A-fragments loaded once, held in regs
// across all 4 r-tiles. E-tile + colGeo double-buffered in LDS; loads for
// tile t+1 issue before tile t's barrier and hide under its epilogue.
__global__ __launch_bounds__(256, 4)
void matching_kernel(const char* __restrict__ wsb, float* __restrict__ out) {
    __shared__ _Float16 ldsE[2][64 * 128];              // 2 x 16 KB
    __shared__ float colL[2][64], colO[2][64], colC[2][64];
    __shared__ float rowLatX[128], rowLonX[128], rowCn[128];
    __shared__ float2 tab2[KD];
    __shared__ float pe[4][64], pw[4][64];

    const int tid = threadIdx.x;
    const int b     = blockIdx.y;
    const int rbase = blockIdx.x * 256;
    const int wv = tid >> 6, lane = tid & 63;
    const int lrow = lane & 15, quad = lane >> 4;

    const _Float16* wsE = (const _Float16*)(wsb + WS_E_OFF);
    const _Float16* wsS = (const _Float16*)(wsb + WS_S_OFF);

    // V: scalar, consumed only by uniform branches much later
    const int V  = ((const int*)(wsb + WS_V_OFF))[b];

    // ---- invariant loads (independent, issue immediately) ----
    float4 rg; float2 t2;
    if (tid >= 128)     rg = ((const float4*)(wsb + WS_RG_OFF))[b * 128 + (tid - 128)];
    else if (tid >= 64) t2 = ((const float2*)(wsb + WS_TAB_OFF))[tid - 64];

    // A fragments: rows wv*16+lrow (tile0) and +64 (tile1), no V dependence
    const _Float16* pA0 = wsS + (size_t)(b * NN + wv * 16 + lrow) * DD;
    f16x8 af0[4], af1[4];
#pragma unroll
    for (int kk = 0; kk < 4; ++kk) {
        af0[kk] = *(const f16x8*)(pA0 + kk * 32 + quad * 8);
        af1[kk] = *(const f16x8*)(pA0 + 64 * DD + kk * 32 + quad * 8);
    }

    // ---- r-tile 0 staged loads ----
    const int srow0 = tid >> 4, scc = tid & 15;        // chunk tc adds 16 rows
    uint4 creg[4];
#pragma unroll
    for (int tc = 0; tc < 4; ++tc)
        creg[tc] = *(const uint4*)(wsE + (size_t)(rbase + srow0 + tc * 16) * DD + scc * 8);
    float4 cg;
    if (tid < 64) cg = ((const float4*)(wsb + WS_CG_OFF))[rbase + tid];

    // ---- store invariants to LDS ----
    if (tid >= 128) { int n = tid - 128; rowLatX[n] = rg.x; rowLonX[n] = rg.y; rowCn[n] = rg.z; }
    else if (tid >= 64) tab2[tid - 64] = t2;

    const int Mt  = (V + 15) >> 4;
    const bool t1a = (wv + 4) < Mt;                    // uniform per wave

    float tlX[8], toX[8], cn8[8];                      // filled after 1st barrier

    for (int t = 0; t < 4; ++t) {
        const int p = t & 1;
        // stage tile t into parity p (swizzled 16B chunks)
#pragma unroll
        for (int tc = 0; tc < 4; ++tc) {
            int sr = srow0 + tc * 16;
            *(uint4*)&ldsE[p][sr * 128 + ((scc ^ (sr & 7)) * 8)] = creg[tc];
        }
        if (tid < 64) { colL[p][tid] = cg.x; colO[p][tid] = cg.y; colC[p][tid] = cg.z; }
        // prefetch tile t+1 (hides under this tile's MFMA+epilogue)
        if (t < 3) {
#pragma unroll
            for (int tc = 0; tc < 4; ++tc)
                creg[tc] = *(const uint4*)(wsE + (size_t)(rbase + (t + 1) * 64 + srow0 + tc * 16) * DD + scc * 8);
            if (tid < 64) cg = ((const float4*)(wsb + WS_CG_OFF))[rbase + (t + 1) * 64 + tid];
        }
        __syncthreads();   // ldsE[p], colgeo[p] ready (t==0: also invariants)

        if (t == 0) {
#pragma unroll
            for (int i = 0; i < 2; ++i)
#pragma unroll
                for (int e = 0; e < 4; ++e) {
                    int n = (wv + 4 * i) * 16 + quad * 4 + e;
                    int j = i * 4 + e;
                    tlX[j] = rowLatX[n]; toX[j] = rowLonX[n]; cn8[j] = rowCn[n];
                }
        }

        // ---- MFMAs ----
        float4v acc[2][4] = {};
#pragma unroll
        for (int kk = 0; kk < 4; ++kk) {
#pragma unroll
            for (int tr = 0; tr < 4; ++tr) {
                int row = tr * 16 + lrow;
                int c = kk * 4 + quad;
                f16x8 bb = *(const f16x8*)&ldsE[p][row * 128 + ((c ^ (lrow & 7)) * 8)];
                acc[0][tr] = __builtin_amdgcn_mfma_f32_16x16x32_f16(af0[kk], bb, acc[0][tr], 0, 0, 0);
                if (t1a)
                    acc[1][tr] = __builtin_amdgcn_mfma_f32_16x16x32_f16(af1[kk], bb, acc[1][tr], 0, 0, 0);
            }
        }

        // ---- single-pass epilogue (exp2 domain) ----
#pragma unroll
        for (int tr = 0; tr < 4; ++tr) {
            int col = tr * 16 + lrow;
            float claX = colL[p][col], cloX = colO[p][col], cc = colC[p][col];
            float es = 0.0f, ws2 = 0.0f;
#pragma unroll
            for (int i = 0; i < 2; ++i) {
                if (i == 1 && !t1a) continue;
#pragma unroll
                for (int e = 0; e < 4; ++e) {
                    int j = i * 4 + e;
                    float hd = claX - tlX[j];
                    float ho = cloX - toX[j];
                    float a  = fmaf(hd, hd, (cn8[j] * cc) * (ho * ho));      // x^2
                    float x  = fminf(__builtin_amdgcn_sqrtf(a), 62.999996f); // NaN->62.99
                    int   k  = (int)x;
                    float fr = x - (float)k;
                    float2 te = tab2[k];
                    float bias2 = fmaf(fr, te.y, te.x);
                    float s2 = fmaf(acc[i][tr][e], SCALE2_C, bias2);
                    float ex = __builtin_amdgcn_exp2f(s2);
                    ex = (cn8[j] < 0.0f) ? 0.0f : ex;  // pad/masked rows
                    es += ex;
                    ws2 = fmaf(ex, s2, ws2);
                }
            }
            es  += __shfl_xor(es, 16, 64);  es  += __shfl_xor(es, 32, 64);
            ws2 += __shfl_xor(ws2, 16, 64); ws2 += __shfl_xor(ws2, 32, 64);
            if (lane < 16) { pe[wv][col] = es; pw[wv][col] = ws2; }
        }
        __syncthreads();   // pe/pw ready; next iter's barrier protects reuse

        if (tid < 64) {
            float es = pe[0][tid] + pe[1][tid] + pe[2][tid] + pe[3][tid];
            float ws = pw[0][tid] + pw[1][tid] + pw[2][tid] + pw[3][tid];
            float o = es > 0.0f ? (ws / es) * LN2_C : 0.0f;
            out[(size_t)b * RR + rbase + t * 64 + tid] = o;
        }
    }
}

extern "C" void kernel_launch(void* const* d_in, const int* in_sizes, int n_in,
                              void* d_out, int out_size, void* d_ws, size_t ws_size,
                              hipStream_t stream) {
    const float* S    = (const float*)d_in[0];
    const float* Remb = (const float*)d_in[1];
    const float* tlat = (const float*)d_in[2];
    const float* tlon = (const float*)d_in[3];
    const float* cent = (const float*)d_in[4];
    const int*   kpm  = (const int*)d_in[5];
    const float* Etab = (const float*)d_in[6];
    float* out = (float*)d_out;
    char* wsb = (char*)d_ws;

    prep_kernel<<<593, 256, 0, stream>>>(S, Remb, tlat, tlon, cent, kpm, Etab, wsb);

    dim3 grid(16, BB, 1);
    matching_kernel<<<grid, dim3(256, 1, 1), 0, stream>>>(wsb, out);
}

// Round 11
// 91.290 us; speedup vs baseline: 1.2711x; 1.2711x over previous
//
#include <hip/hip_runtime.h>
#include <math.h>

// Problem constants (from reference). All float tensors f32; mask int; out f32.
#define BB 64
#define NN 128
#define DD 128
#define RR 4096
#define KD 64

typedef _Float16 f16x8 __attribute__((ext_vector_type(8)));
typedef _Float16 f16x4 __attribute__((ext_vector_type(4)));
typedef float    float4v __attribute__((ext_vector_type(4)));

// ---- ws layout (byte offsets) ----
#define WS_E_OFF   0                                  // E f16 (R*D), 1 MB
#define WS_S_OFF   (1048576)                          // S f16 compacted, 2 MB
#define WS_CG_OFF  (3145728)                          // colGeo float4 (R), 64 KB
#define WS_RG_OFF  (3145728 + 65536)                  // rowGeo float4 (B*128), 128 KB
#define WS_TAB_OFF (3145728 + 65536 + 131072)         // tab2 float2 (KD), 512 B
#define WS_V_OFF   (3145728 + 65536 + 131072 + 512)   // V int (B), 256 B

#define D2R_C    0.017453292519943295f                // pi/180
#define HSC_C    (0.008726646259971648f * 4013.73f)   // (pi/360)*2*Re*(63/200)
#define L2E_C    1.4426950408889634f
#define SCALE2_C (0.08838834764831845f * 1.4426950408889634f)
#define LN2_C    0.6931471805599453f

// Pre-pass: E->f16, per-b valid-row compaction of S (f32->f16), per-b rowGeo,
// per-r colGeo, exp2-domain bias table. 593 blocks x 256.
__global__ __launch_bounds__(256)
void prep_kernel(const float* __restrict__ S, const float* __restrict__ E,
                 const float* __restrict__ tlat, const float* __restrict__ tlon,
                 const float* __restrict__ cent, const int* __restrict__ kpm,
                 const float* __restrict__ Etab, char* __restrict__ wsb) {
    const int blk = blockIdx.x, tid = threadIdx.x;
    if (blk < 512) {                       // E convert: 512*256 = 131072 float4s
        int i = blk * 256 + tid;
        float4 v = ((const float4*)E)[i];
        f16x4 h = {(_Float16)v.x, (_Float16)v.y, (_Float16)v.z, (_Float16)v.w};
        ((f16x4*)(wsb + WS_E_OFF))[i] = h;
    } else if (blk < 528) {                // colGeo: 16*256 = 4096
        int r = (blk - 512) * 256 + tid;
        float cla = cent[2 * r], clo = cent[2 * r + 1];
        ((float4*)(wsb + WS_CG_OFF))[r] =
            make_float4(cla * HSC_C, clo * HSC_C, cosf(cla * D2R_C), 0.0f);
    } else if (blk == 528) {               // tab2
        if (tid < KD) {
            float lo = Etab[tid];
            float hi = Etab[tid < KD - 1 ? tid + 1 : KD - 1];
            ((float2*)(wsb + WS_TAB_OFF))[tid] =
                make_float2(lo * L2E_C, (hi - lo) * L2E_C);
        }
    } else {                               // per-b compaction: blk-529 = b
        __shared__ int idx[128];
        __shared__ unsigned long long smask[2];
        const int b = blk - 529;
        const int wv = tid >> 6, lane = tid & 63;
        if (tid < 128) {
            bool valid = (kpm[b * NN + tid] == 0);
            unsigned long long m = __ballot(valid);
            if (lane == 0) smask[wv] = m;
        }
        __syncthreads();
        const unsigned long long m0 = smask[0], m1 = smask[1];
        const int c0 = __popcll(m0);
        const int V  = c0 + __popcll(m1);
        if (tid == 0) ((int*)(wsb + WS_V_OFF))[b] = V;
        if (tid < 128) {
            unsigned long long mw = (tid < 64) ? m0 : m1;
            int ln = tid & 63;
            if ((mw >> ln) & 1ull) {
                int pos = __popcll(mw & ((1ull << ln) - 1ull)) + (tid < 64 ? 0 : c0);
                idx[pos] = tid;
            }
        }
        __syncthreads();
        if (tid < 128) {                   // compacted row geo (pads cn=-1)
            float4 rg;
            if (tid < V) {
                int n = idx[tid];
                float la = tlat[b * NN + n], lo = tlon[b * NN + n];
                rg = make_float4(la * HSC_C, lo * HSC_C, cosf(la * D2R_C), 0.0f);
            } else rg = make_float4(0.0f, 0.0f, -1.0f, 0.0f);
            ((float4*)(wsb + WS_RG_OFF))[b * 128 + tid] = rg;
        }
        // compact-copy S rows, f32 -> f16
        f16x4* dst = (f16x4*)(wsb + WS_S_OFF) + (size_t)b * NN * (DD / 4);
        const float4* src = (const float4*)S + (size_t)b * NN * (DD / 4);
        for (int ch = tid; ch < V * 32; ch += 256) {
            int row = ch >> 5, cp = ch & 31;
            float4 v = src[idx[row] * 32 + cp];
            f16x4 h = {(_Float16)v.x, (_Float16)v.y, (_Float16)v.z, (_Float16)v.w};
            dst[row * 32 + cp] = h;
        }
    }
}

// One block per (b, 64-col r-tile). 256 threads = 4 waves. R8 structure with
// the spill fix: __launch_bounds__(256,3) -> ~170-reg unified cap (demand ~140)
// so NO scratch spills (R10's 76 MB WRITE_SIZE was spill traffic at the
// 128-reg cap of (256,4)). 3 blocks/CU; LDS ~21 KB not binding.
__global__ __launch_bounds__(256, 3)
void matching_kernel(const char* __restrict__ wsb, float* __restrict__ out) {
    __shared__ _Float16 ldsE[64 * 128];                 // 16 KB
    __shared__ float colLatX[64], colLonX[64], colCos[64];
    __shared__ float rowLatX[128], rowLonX[128], rowCn[128];
    __shared__ float2 tab2[KD];
    __shared__ float pe[4][64], pw[4][64];

    const int tid = threadIdx.x;
    const int b  = blockIdx.y;
    const int r0 = blockIdx.x * 64;
    const int wv = tid >> 6, lane = tid & 63;
    const int lrow = lane & 15, quad = lane >> 4;

    const _Float16* wsE = (const _Float16*)(wsb + WS_E_OFF);
    const _Float16* wsS = (const _Float16*)(wsb + WS_S_OFF);

    // scalar V load: issued now, consumed by uniform branches
    const int V  = ((const int*)(wsb + WS_V_OFF))[b];

    // ---- issue E-tile loads (4 x 16B per thread), independent ----
    uint4 creg[4];
#pragma unroll
    for (int t = 0; t < 4; ++t) {
        int i = tid + t * 256;
        creg[t] = *(const uint4*)(wsE + (size_t)(r0 + (i >> 4)) * DD + (i & 15) * 8);
    }
    // ---- issue geo/table loads, independent ----
    float4 cg, rg; float2 t2;
    if (tid < 64)        cg = ((const float4*)(wsb + WS_CG_OFF))[r0 + tid];
    else if (tid < 128)  t2 = ((const float2*)(wsb + WS_TAB_OFF))[tid - 64];
    else                 rg = ((const float4*)(wsb + WS_RG_OFF))[b * 128 + (tid - 128)];

    const int Mt = (V + 15) >> 4;
    const bool t1a = (wv + 4) < Mt;        // uniform per wave

    // ---- A fragments: rows wv*16+lrow (tile0 always, tile1 if active) ----
    const _Float16* pA0 = wsS + (size_t)(b * NN + wv * 16 + lrow) * DD;
    f16x8 af0[4], af1[4];
#pragma unroll
    for (int kk = 0; kk < 4; ++kk)
        af0[kk] = *(const f16x8*)(pA0 + kk * 32 + quad * 8);
    if (t1a) {
#pragma unroll
        for (int kk = 0; kk < 4; ++kk)
            af1[kk] = *(const f16x8*)(pA0 + 64 * DD + kk * 32 + quad * 8);
    }

    // ---- LDS stores (XOR-swizzled 16B chunks) ----
#pragma unroll
    for (int t = 0; t < 4; ++t) {
        int i = tid + t * 256, sr = i >> 4, sc = i & 15;
        *(uint4*)&ldsE[sr * DD + ((sc ^ (sr & 7)) * 8)] = creg[t];
    }
    if (tid < 64) { colLatX[tid] = cg.x; colLonX[tid] = cg.y; colCos[tid] = cg.z; }
    else if (tid < 128) tab2[tid - 64] = t2;
    else { int n = tid - 128; rowLatX[n] = rg.x; rowLonX[n] = rg.y; rowCn[n] = rg.z; }
    __syncthreads();   // the only pre-epilogue barrier

    // ---- MFMAs ----
    float4v acc[2][4] = {};
#pragma unroll
    for (int kk = 0; kk < 4; ++kk) {
#pragma unroll
        for (int tr = 0; tr < 4; ++tr) {
            int row = tr * 16 + lrow;
            int c = kk * 4 + quad;
            f16x8 bb = *(const f16x8*)&ldsE[row * DD + ((c ^ (lrow & 7)) * 8)];
            acc[0][tr] = __builtin_amdgcn_mfma_f32_16x16x32_f16(af0[kk], bb, acc[0][tr], 0, 0, 0);
            if (t1a)
                acc[1][tr] = __builtin_amdgcn_mfma_f32_16x16x32_f16(af1[kk], bb, acc[1][tr], 0, 0, 0);
        }
    }

    // ---- per-lane row geo (8 compacted rows) ----
    float tlX[8], toX[8], cn8[8];
#pragma unroll
    for (int i = 0; i < 2; ++i)
#pragma unroll
        for (int e = 0; e < 4; ++e) {
            int n = (wv + 4 * i) * 16 + quad * 4 + e;
            int j = i * 4 + e;
            tlX[j] = rowLatX[n]; toX[j] = rowLonX[n]; cn8[j] = rowCn[n];
        }

    // ---- single-pass epilogue (exp2 domain) ----
#pragma unroll
    for (int tr = 0; tr < 4; ++tr) {
        int col = tr * 16 + lrow;
        float claX = colLatX[col], cloX = colLonX[col], cc = colCos[col];
        float es = 0.0f, ws2 = 0.0f;
#pragma unroll
        for (int i = 0; i < 2; ++i) {
            if (i == 1 && !t1a) continue;
#pragma unroll
            for (int e = 0; e < 4; ++e) {
                int j = i * 4 + e;
                float hd = claX - tlX[j];
                float ho = cloX - toX[j];
                float a  = fmaf(hd, hd, (cn8[j] * cc) * (ho * ho));      // x^2
                float x  = fminf(__builtin_amdgcn_sqrtf(a), 62.999996f); // NaN->62.99
                int   k  = (int)x;
                float fr = x - (float)k;
                float2 te = tab2[k];
                float bias2 = fmaf(fr, te.y, te.x);
                float s2 = fmaf(acc[i][tr][e], SCALE2_C, bias2);
                float ex = __builtin_amdgcn_exp2f(s2);
                ex = (cn8[j] < 0.0f) ? 0.0f : ex;   // pad/masked rows
                es += ex;
                ws2 = fmaf(ex, s2, ws2);
            }
        }
        es  += __shfl_xor(es, 16, 64);  es  += __shfl_xor(es, 32, 64);
        ws2 += __shfl_xor(ws2, 16, 64); ws2 += __shfl_xor(ws2, 32, 64);
        if (lane < 16) { pe[wv][col] = es; pw[wv][col] = ws2; }
    }
    __syncthreads();

    if (tid < 64) {
        float es = pe[0][tid] + pe[1][tid] + pe[2][tid] + pe[3][tid];
        float ws = pw[0][tid] + pw[1][tid] + pw[2][tid] + pw[3][tid];
        float o = es > 0.0f ? (ws / es) * LN2_C : 0.0f;
        out[(size_t)b * RR + r0 + tid] = o;
    }
}

extern "C" void kernel_launch(void* const* d_in, const int* in_sizes, int n_in,
                              void* d_out, int out_size, void* d_ws, size_t ws_size,
                              hipStream_t stream) {
    const float* S    = (const float*)d_in[0];
    const float* Remb = (const float*)d_in[1];
    const float* tlat = (const float*)d_in[2];
    const float* tlon = (const float*)d_in[3];
    const float* cent = (const float*)d_in[4];
    const int*   kpm  = (const int*)d_in[5];
    const float* Etab = (const float*)d_in[6];
    float* out = (float*)d_out;
    char* wsb = (char*)d_ws;

    prep_kernel<<<593, 256, 0, stream>>>(S, Remb, tlat, tlon, cent, kpm, Etab, wsb);

    dim3 grid(RR / 64, BB, 1);
    matching_kernel<<<grid, dim3(256, 1, 1), 0, stream>>>(wsb, out);
}